// Round 8
// baseline (376.969 us; speedup 1.0000x reference)
//
#include <hip/hip_runtime.h>
#include <stdint.h>

// Problem constants (fixed by setup_inputs)
#define DD   128      // feature dim D
#define TT   64       // time steps
#define BB   8192     // batch
#define NPOW 8        // Taylor degree for expm: ||tW||<=~1.3 -> remainder 1.3^9/9! ~ 3e-5

typedef float  f32x4  __attribute__((ext_vector_type(4)));
typedef __bf16 bf16x8 __attribute__((ext_vector_type(8)));

// RTN-even float -> bf16 bits
__device__ __forceinline__ unsigned short f2bf(float f) {
  unsigned u = __builtin_bit_cast(unsigned, f);
  u += 0x7fffu + ((u >> 16) & 1u);
  return (unsigned short)(u >> 16);
}

// ---------------------------------------------------------------------------
// x (fp32) -> xb (bf16 bits), 8192x128, 4 elems/thread, fully coalesced
// ---------------------------------------------------------------------------
__global__ void cvt_x_kernel(const float* __restrict__ x, unsigned short* __restrict__ xb) {
  int i = (blockIdx.x * 256 + threadIdx.x) * 4;
  float4 v = *(const float4*)(x + i);
  unsigned long long u =  (unsigned long long)f2bf(v.x)
                       | ((unsigned long long)f2bf(v.y) << 16)
                       | ((unsigned long long)f2bf(v.z) << 32)
                       | ((unsigned long long)f2bf(v.w) << 48);
  *(unsigned long long*)(xb + i) = u;
}

// ---------------------------------------------------------------------------
// Wt = W^T (128x128 fp32). grid 16 blocks of 32x32 tiles, 256 threads.
// ---------------------------------------------------------------------------
__global__ void transpose_kernel(const float* __restrict__ W, float* __restrict__ Wt) {
  __shared__ float t[32][33];
  int bx = blockIdx.x & 3, by = blockIdx.x >> 2;
  int r = threadIdx.x >> 3;          // 0..31
  int c = (threadIdx.x & 7) * 4;     // 4 cols/thread
  float4 v = *(const float4*)(W + (by * 32 + r) * DD + bx * 32 + c);
  t[r][c] = v.x; t[r][c + 1] = v.y; t[r][c + 2] = v.z; t[r][c + 3] = v.w;
  __syncthreads();
  float4 o = { t[c + 0][r], t[c + 1][r], t[c + 2][r], t[c + 3][r] };
  *(float4*)(Wt + (bx * 32 + r) * DD + by * 32 + c) = o;
}

// ---------------------------------------------------------------------------
// fp32 power ladder on W^T. Wp slot (n-1) holds (W^T)^n.
// ---------------------------------------------------------------------------
__global__ __launch_bounds__(256) void powmm_kernel(float* __restrict__ Wp,
                                                    int aPow, int bBase, int dstBase) {
  int mat = blockIdx.x >> 4;
  int rb  = blockIdx.x & 15;
  const float* A = Wp + (aPow - 1) * DD * DD;
  const float* B = Wp + (bBase + mat - 1) * DD * DD;
  float* C = Wp + (dstBase + mat - 1) * DD * DD;

  __shared__ float Bs[DD * DD];      // 64 KB
  __shared__ float As[8 * DD];       // 4 KB
  for (int i = threadIdx.x; i < DD * DD / 4; i += 256)
    ((float4*)Bs)[i] = ((const float4*)B)[i];
  for (int i = threadIdx.x; i < 8 * DD / 4; i += 256)
    ((float4*)As)[i] = ((const float4*)(A + rb * 8 * DD))[i];
  __syncthreads();

  int r  = threadIdx.x >> 5;         // 0..7 local row
  int c0 = (threadIdx.x & 31) * 4;   // 4 cols/thread
  f32x4 acc = {0.f, 0.f, 0.f, 0.f};
  for (int k = 0; k < DD; ++k) {
    float a = As[r * DD + k];
    f32x4 b = *(const f32x4*)(Bs + k * DD + c0);
    acc += a * b;
  }
  *(f32x4*)(C + (rb * 8 + r) * DD + c0) = acc;
}

// ---------------------------------------------------------------------------
// Combine: P_j^T = I + sum_{n=1..8} (t^n/n!) (W^T)^n,  t = j*0.01, bf16 out.
// ---------------------------------------------------------------------------
__global__ __launch_bounds__(256) void combine_kernel(const float* __restrict__ Wp,
                                                      unsigned short* __restrict__ Pb) {
  int j    = blockIdx.x >> 4;
  int part = blockIdx.x & 15;
  float c[NPOW];
  double t = (double)j * 0.01, cc = 1.0;
  for (int n = 1; n <= NPOW; ++n) { cc *= t / (double)n; c[n - 1] = (float)cc; }

  int e0 = part * 1024 + threadIdx.x * 4;   // element offset within 128x128
  f32x4 acc;
#pragma unroll
  for (int i = 0; i < 4; ++i) {
    int e = e0 + i;
    acc[i] = ((e >> 7) == (e & 127)) ? 1.0f : 0.0f;   // identity
  }
#pragma unroll
  for (int n = 0; n < NPOW; ++n) {
    f32x4 w = *(const f32x4*)(Wp + n * DD * DD + e0);
    acc += c[n] * w;
  }
  unsigned long long u =  (unsigned long long)f2bf(acc[0])
                       | ((unsigned long long)f2bf(acc[1]) << 16)
                       | ((unsigned long long)f2bf(acc[2]) << 32)
                       | ((unsigned long long)f2bf(acc[3]) << 48);
  *(unsigned long long*)(Pb + j * DD * DD + e0) = u;
}

// ---------------------------------------------------------------------------
// Main GEMM, j-SWEEP-PER-BLOCK variant (R7):
//   out[b, j*128+d] = sum_k xb[b,k] * Pb[j][d,k]
// Grid = 512 blocks; block bt owns batch rows [bt*16, bt*16+16) and sweeps
// ALL j=0..63 -> writes a CONTIGUOUS 512 KiB output region, each row filled
// left-to-right in sequential 512B steps (DRAM-page friendly, matching the
// fill kernel's 6.4 TB/s access pattern). Each 128B line completed by one
// wave in 2 back-to-back stores.
// A-fragments (16 rows) load ONCE into registers; P_j (32 KB, L2-hot) read
// per block per j: 512 blocks * 2 MiB = 1 GiB L2 reads ~ 29 us @ L2 BW,
// below the 42 us write floor.
// Waves split the d-dimension: wave w covers d in [w*32, w*32+32).
// Swapped-operand MFMA (validated R4/R5): m = li (af row), d = nq + nt*16 +
// quad*4 + r (bf row) -> direct aligned float4 plain stores.
// ---------------------------------------------------------------------------
__global__ __launch_bounds__(256) void gemm_kernel(
    const unsigned short* __restrict__ xb,   // 8192 x 128 bf16 row-major
    const unsigned short* __restrict__ Pb,   // 64 x (128 d x 128 k) bf16 (P^T per j)
    float* __restrict__ out) {               // 8192 x (64*128) fp32
  const int bt   = blockIdx.x;     // 0..511, 16 batch rows each
  const int tid  = threadIdx.x;
  const int w    = tid >> 6;       // wave 0..3
  const int l    = tid & 63;
  const int quad = l >> 4;         // 0..3
  const int li   = l & 15;
  const int nq   = w * 32;         // wave's 32-col (d) slice of each P_j

  // A fragments: row m = bt*16 + li, cols k = ks*32 + quad*8 (+0..7).
  const unsigned short* gA = xb + (size_t)(bt * 16) * DD;
  bf16x8 af[4];
#pragma unroll
  for (int ks = 0; ks < 4; ++ks)
    af[ks] = *(const bf16x8*)(gA + li * DD + ks * 32 + quad * 8);

  const size_t orow = (size_t)(TT * DD);    // 8192 floats per batch row
  float* orow_p = out + (size_t)(bt * 16 + li) * orow + nq + quad * 4;

#pragma unroll 1
  for (int j = 0; j < TT; ++j) {
    const unsigned short* gB = Pb + j * DD * DD;
    f32x4 acc0 = {0.f, 0.f, 0.f, 0.f};
    f32x4 acc1 = {0.f, 0.f, 0.f, 0.f};
#pragma unroll
    for (int ks = 0; ks < 4; ++ks) {
      bf16x8 bf0 = *(const bf16x8*)(gB + (nq +  0 + li) * DD + ks * 32 + quad * 8);
      bf16x8 bf1 = *(const bf16x8*)(gB + (nq + 16 + li) * DD + ks * 32 + quad * 8);
      acc0 = __builtin_amdgcn_mfma_f32_16x16x32_bf16(bf0, af[ks], acc0, 0, 0, 0);
      acc1 = __builtin_amdgcn_mfma_f32_16x16x32_bf16(bf1, af[ks], acc1, 0, 0, 0);
    }
    // d = nq + nt*16 + quad*4 + r ; store at out[m][j*128 + d]
    *(f32x4*)(orow_p + j * DD)      = acc0;
    *(f32x4*)(orow_p + j * DD + 16) = acc1;
  }
}

// ---------------------------------------------------------------------------
extern "C" void kernel_launch(void* const* d_in, const int* in_sizes, int n_in,
                              void* d_out, int out_size, void* d_ws, size_t ws_size,
                              hipStream_t stream) {
  const float* x = (const float*)d_in[0];
  const float* W = (const float*)d_in[1];
  float* out = (float*)d_out;

  // Workspace: Wp = 8 fp32 128x128 slots ((W^T)^1..(W^T)^8) = 512 KB,
  //            Pb = 64 * 128*128 bf16 = 2 MiB,  xb = 8192*128 bf16 = 2 MiB
  float* Wp = (float*)d_ws;
  unsigned short* Pb = (unsigned short*)((char*)d_ws + NPOW * DD * DD * sizeof(float));
  unsigned short* xb = Pb + TT * DD * DD;

  cvt_x_kernel<<<BB * DD / (256 * 4), 256, 0, stream>>>(x, xb);
  transpose_kernel<<<16, 256, 0, stream>>>(W, Wp);          // slot 0 = W^T

  // log-depth ladder on W^T: n=2 | n=3,4 | n=5..8
  powmm_kernel<<<16, 256, 0, stream>>>(Wp, 1, 1, 2);
  powmm_kernel<<<32, 256, 0, stream>>>(Wp, 2, 1, 3);
  powmm_kernel<<<64, 256, 0, stream>>>(Wp, 4, 1, 5);

  combine_kernel<<<TT * 16, 256, 0, stream>>>(Wp, Pb);

  gemm_kernel<<<BB / 16, 256, 0, stream>>>(xb, Pb, out);
}